// Round 3
// baseline (108.650 us; speedup 1.0000x reference)
//
#include <hip/hip_runtime.h>
#include <math.h>

#define C 32
#define OUT_DIM 288

__device__ __forceinline__ float gelu_tanh(float x) {
    // jax.nn.gelu approximate=True
    float x3 = x * x * x;
    float t = tanhf(0.7978845608028654f * (x + 0.044715f * x3));
    return 0.5f * x * (1.0f + t);
}

__global__ void hist_kernel(const int* __restrict__ recv, int E, int* __restrict__ counts) {
    int e = blockIdx.x * 256 + threadIdx.x;
    if (e < E) atomicAdd(&counts[recv[e]], 1);
}

// One-block scan, 1024 threads, ~10 elems/thread:
// offsets[i+1] = inclusive prefix, cursor[i] = exclusive prefix, offsets[0]=0
__global__ __launch_bounds__(1024) void scan_kernel(
    const int* __restrict__ counts, int* __restrict__ offsets,
    int* __restrict__ cursor, int n)
{
    __shared__ int wbase[17];
    __shared__ int wtot[16];
    const int tid = threadIdx.x;
    const int lane = tid & 63;
    const int wid = tid >> 6;
    const int chunk = (n + 1023) >> 10;
    const int base = tid * chunk;

    int sum = 0;
    for (int i = 0; i < chunk; ++i) {
        int idx = base + i;
        if (idx < n) sum += counts[idx];
    }
    int v = sum;
    for (int off = 1; off < 64; off <<= 1) {
        int u = __shfl_up(v, off, 64);
        if (lane >= off) v += u;
    }
    if (lane == 63) wtot[wid] = v;
    __syncthreads();
    if (tid == 0) {
        int acc = 0;
        for (int w2 = 0; w2 < 16; ++w2) { wbase[w2] = acc; acc += wtot[w2]; }
    }
    __syncthreads();
    int run = wbase[wid] + (v - sum);
    for (int i = 0; i < chunk; ++i) {
        int idx = base + i;
        if (idx < n) {
            int cv = counts[idx];
            cursor[idx] = run;
            run += cv;
            offsets[idx + 1] = run;
        }
    }
    if (tid == 0) offsets[0] = 0;
}

// Scatter + spherical-harmonic precompute: adj[p] = {shx, shy, shz, sender_bits}
__global__ void scatter_sh_kernel(const int* __restrict__ recv,
                                  const int* __restrict__ senders,
                                  const float* __restrict__ pos, int E,
                                  int* __restrict__ cursor, float4* __restrict__ adj) {
    int e = blockIdx.x * 256 + threadIdx.x;
    if (e < E) {
        const int r = recv[e];
        const int s = senders[e];
        const float rx = pos[r * 3 + 0] - pos[s * 3 + 0];
        const float ry = pos[r * 3 + 1] - pos[s * 3 + 1];
        const float rz = pos[r * 3 + 2] - pos[s * 3 + 2];
        const float nrm = sqrtf(rx * rx + ry * ry + rz * rz);
        const float f = 1.7320508075688772f / fmaxf(nrm, 1e-9f);  // sqrt(3)/|r|
        const int p = atomicAdd(&cursor[r], 1);
        adj[p] = make_float4(rx * f, ry * f, rz * f, __int_as_float(s));
    }
}

// 2 nodes per block, 2 waves per node (portion split), lane = half*32 + c.
// Each (portion,half) handles edges k ≡ beg+portion*2+half (mod 4).
// Partials -> LDS, linear phases split 4-ways across the node's 2 waves x 2 halves.
__global__ __launch_bounds__(256) void agg_node_kernel(
    const float* __restrict__ node0, const float* __restrict__ node1,
    const int* __restrict__ offsets, const float4* __restrict__ adj,
    const float* __restrict__ Wpre0, const float* __restrict__ Wpre1,
    const float* __restrict__ Wpre2,
    const float* __restrict__ Wpost0, const float* __restrict__ Wpost1,
    const float* __restrict__ Wpost2,
    const float* __restrict__ Wsc0, const float* __restrict__ Wsc1,
    float* __restrict__ out, int N)
{
    __shared__ float prt[2][2][13][32];  // [slot][portion][arr][c] edge partials (pre-scaled)
    __shared__ float sxn[2][4][32];      // [slot][{x0,x1x,x1y,x1z}][c] node's own features
    __shared__ float shh[2][9][32];      // [slot][{h0,h1x,h1y,h1z,h2v0..4}][d]

    const int tid     = threadIdx.x;
    const int wv      = tid >> 6;
    const int slot    = wv >> 1;
    const int portion = wv & 1;
    const int lane    = tid & 63;
    const int half    = lane >> 5;
    const int c       = lane & 31;
    const int node    = blockIdx.x * 2 + slot;
    const bool valid  = (node < N);

    const float S2 = 0.70710678118654752f;   // 1/sqrt(2)
    const float S6 = 0.40824829046386302f;   // 1/sqrt(6)
    const float INV_SQRT3 = 0.57735026918962576f;
    const float INV_DEN = 1.0f / 16.0f;

    float ax0 = 0.f, atp0 = 0.f;
    float ax1x = 0.f, ax1y = 0.f, ax1z = 0.f;
    float at1x = 0.f, at1y = 0.f, at1z = 0.f;
    float a2v0 = 0.f, a2v1 = 0.f, a2v2 = 0.f, a2v3 = 0.f, a2v4 = 0.f;

#define EDGE_ACC(A, X0, U1)                                                 \
    {                                                                       \
        const float shx = (A).x, shy = (A).y, shz = (A).z;                  \
        ax0 += (X0);                                                        \
        atp0 += (U1).x * shx + (U1).y * shy + (U1).z * shz;                 \
        ax1x += (U1).x; ax1y += (U1).y; ax1z += (U1).z;                     \
        at1x += (X0) * shx; at1y += (X0) * shy; at1z += (X0) * shz;         \
        a2v0 += S2 * ((U1).x * shy + (U1).y * shx);                         \
        a2v1 += S2 * ((U1).y * shz + (U1).z * shy);                         \
        a2v2 += S6 * (2.f * (U1).z * shz - (U1).x * shx - (U1).y * shy);    \
        a2v3 += S2 * ((U1).x * shz + (U1).z * shx);                         \
        a2v4 += S2 * ((U1).x * shx - (U1).y * shy);                         \
    }

    if (valid) {
        const int end = offsets[node + 1];
        int k = offsets[node] + portion * 2 + half;   // stride 4
        while (k + 12 < end) {
            const float4 A0 = adj[k];
            const float4 A1 = adj[k + 4];
            const float4 A2 = adj[k + 8];
            const float4 A3 = adj[k + 12];
            const int b0 = __float_as_int(A0.w) * C + c;
            const int b1 = __float_as_int(A1.w) * C + c;
            const int b2 = __float_as_int(A2.w) * C + c;
            const int b3 = __float_as_int(A3.w) * C + c;
            const float q0 = node0[b0];
            const float q1 = node0[b1];
            const float q2 = node0[b2];
            const float q3 = node0[b3];
            const float3 u0 = *(const float3*)(node1 + b0 * 3);
            const float3 u1 = *(const float3*)(node1 + b1 * 3);
            const float3 u2 = *(const float3*)(node1 + b2 * 3);
            const float3 u3 = *(const float3*)(node1 + b3 * 3);
            EDGE_ACC(A0, q0, u0);
            EDGE_ACC(A1, q1, u1);
            EDGE_ACC(A2, q2, u2);
            EDGE_ACC(A3, q3, u3);
            k += 16;
        }
        while (k < end) {
            const float4 A0 = adj[k];
            const int b0 = __float_as_int(A0.w) * C + c;
            const float q0 = node0[b0];
            const float3 u0 = *(const float3*)(node1 + b0 * 3);
            EDGE_ACC(A0, q0, u0);
            k += 4;
        }
    }
#undef EDGE_ACC

    // combine halves (totals land in both halves)
    ax0  += __shfl_xor(ax0, 32, 64);
    atp0 += __shfl_xor(atp0, 32, 64);
    ax1x += __shfl_xor(ax1x, 32, 64);
    ax1y += __shfl_xor(ax1y, 32, 64);
    ax1z += __shfl_xor(ax1z, 32, 64);
    at1x += __shfl_xor(at1x, 32, 64);
    at1y += __shfl_xor(at1y, 32, 64);
    at1z += __shfl_xor(at1z, 32, 64);
    a2v0 += __shfl_xor(a2v0, 32, 64);
    a2v1 += __shfl_xor(a2v1, 32, 64);
    a2v2 += __shfl_xor(a2v2, 32, 64);
    a2v3 += __shfl_xor(a2v3, 32, 64);
    a2v4 += __shfl_xor(a2v4, 32, 64);

    if (half == 0) {
        float* p = &prt[slot][portion][0][c];
        p[0 * 32]  = ax0 * INV_DEN;
        p[1 * 32]  = atp0 * (INV_DEN * INV_SQRT3);
        p[2 * 32]  = ax1x * INV_DEN;
        p[3 * 32]  = ax1y * INV_DEN;
        p[4 * 32]  = ax1z * INV_DEN;
        p[5 * 32]  = at1x * INV_DEN;
        p[6 * 32]  = at1y * INV_DEN;
        p[7 * 32]  = at1z * INV_DEN;
        p[8 * 32]  = a2v0 * INV_DEN;
        p[9 * 32]  = a2v1 * INV_DEN;
        p[10 * 32] = a2v2 * INV_DEN;
        p[11 * 32] = a2v3 * INV_DEN;
        p[12 * 32] = a2v4 * INV_DEN;
    } else if (portion == 0) {
        float x0n = 0.f, x1nx = 0.f, x1ny = 0.f, x1nz = 0.f;
        if (valid) {
            x0n = node0[node * C + c];
            const int b = (node * C + c) * 3;
            x1nx = node1[b + 0]; x1ny = node1[b + 1]; x1nz = node1[b + 2];
        }
        sxn[slot][0][c] = x0n;
        sxn[slot][1][c] = x1nx;
        sxn[slot][2][c] = x1ny;
        sxn[slot][3][c] = x1nz;
    }
    __syncthreads();

#define PRT(j, c2) (prt[slot][0][j][c2] + prt[slot][1][j][c2])

    const int d = c;
    // pre-linear, 4-way split: (portion,half) -> outputs
    if (portion == 0) {
        if (half == 0) {          // h0 (gelu), h1x
            float h0p = 0.f, h1x = 0.f;
#pragma unroll 8
            for (int c2 = 0; c2 < C; ++c2) {
                h0p += PRT(0, c2) * Wpre0[c2 * C + d] + PRT(1, c2) * Wpre0[(C + c2) * C + d];
                h1x += PRT(2, c2) * Wpre1[c2 * C + d] + PRT(5, c2) * Wpre1[(C + c2) * C + d];
            }
            shh[slot][0][d] = gelu_tanh(h0p);
            shh[slot][1][d] = h1x;
        } else {                  // h1y, h1z
            float h1y = 0.f, h1z = 0.f;
#pragma unroll 8
            for (int c2 = 0; c2 < C; ++c2) {
                const float wa1 = Wpre1[c2 * C + d];
                const float wb1 = Wpre1[(C + c2) * C + d];
                h1y += PRT(3, c2) * wa1 + PRT(6, c2) * wb1;
                h1z += PRT(4, c2) * wa1 + PRT(7, c2) * wb1;
            }
            shh[slot][2][d] = h1y;
            shh[slot][3][d] = h1z;
        }
    } else {
        if (half == 0) {          // h2 v0..v2
            float h2a = 0.f, h2b = 0.f, h2c = 0.f;
#pragma unroll 8
            for (int c2 = 0; c2 < C; ++c2) {
                const float w2 = Wpre2[c2 * C + d];
                h2a += PRT(8, c2) * w2;
                h2b += PRT(9, c2) * w2;
                h2c += PRT(10, c2) * w2;
            }
            shh[slot][4][d] = h2a;
            shh[slot][5][d] = h2b;
            shh[slot][6][d] = h2c;
        } else {                  // h2 v3..v4
            float h2d = 0.f, h2e = 0.f;
#pragma unroll 8
            for (int c2 = 0; c2 < C; ++c2) {
                const float w2 = Wpre2[c2 * C + d];
                h2d += PRT(11, c2) * w2;
                h2e += PRT(12, c2) * w2;
            }
            shh[slot][7][d] = h2d;
            shh[slot][8][d] = h2e;
        }
    }
#undef PRT
    __syncthreads();

    // post-linear + shortcut, same 4-way split
    float* po = out + (size_t)node * OUT_DIM;
    if (portion == 0) {
        if (half == 0) {          // o0, o1x
            float o0 = 0.f, o1x = 0.f;
#pragma unroll 8
            for (int c2 = 0; c2 < C; ++c2) {
                o0  += shh[slot][0][c2] * Wpost0[c2 * C + d] + sxn[slot][0][c2] * Wsc0[c2 * C + d];
                o1x += shh[slot][1][c2] * Wpost1[c2 * C + d] + sxn[slot][1][c2] * Wsc1[c2 * C + d];
            }
            if (valid) {
                po[d] = o0;
                po[32 + d * 3 + 0] = o1x;
            }
        } else {                  // o1y, o1z
            float o1y = 0.f, o1z = 0.f;
#pragma unroll 8
            for (int c2 = 0; c2 < C; ++c2) {
                const float wp1 = Wpost1[c2 * C + d];
                const float ws1 = Wsc1[c2 * C + d];
                o1y += shh[slot][2][c2] * wp1 + sxn[slot][2][c2] * ws1;
                o1z += shh[slot][3][c2] * wp1 + sxn[slot][3][c2] * ws1;
            }
            if (valid) {
                po[32 + d * 3 + 1] = o1y;
                po[32 + d * 3 + 2] = o1z;
            }
        }
    } else {
        if (half == 0) {          // o2 v0..v2
            float oa = 0.f, ob = 0.f, oc = 0.f;
#pragma unroll 8
            for (int c2 = 0; c2 < C; ++c2) {
                const float wp2 = Wpost2[c2 * C + d];
                oa += shh[slot][4][c2] * wp2;
                ob += shh[slot][5][c2] * wp2;
                oc += shh[slot][6][c2] * wp2;
            }
            if (valid) {
                po[128 + d * 5 + 0] = oa;
                po[128 + d * 5 + 1] = ob;
                po[128 + d * 5 + 2] = oc;
            }
        } else {                  // o2 v3..v4
            float od = 0.f, oe = 0.f;
#pragma unroll 8
            for (int c2 = 0; c2 < C; ++c2) {
                const float wp2 = Wpost2[c2 * C + d];
                od += shh[slot][7][c2] * wp2;
                oe += shh[slot][8][c2] * wp2;
            }
            if (valid) {
                po[128 + d * 5 + 3] = od;
                po[128 + d * 5 + 4] = oe;
            }
        }
    }
}

extern "C" void kernel_launch(void* const* d_in, const int* in_sizes, int n_in,
                              void* d_out, int out_size, void* d_ws, size_t ws_size,
                              hipStream_t stream) {
    const float* node0   = (const float*)d_in[0];
    const float* node1   = (const float*)d_in[1];
    const float* pos     = (const float*)d_in[2];
    const int*   senders = (const int*)d_in[3];
    const int*   recv    = (const int*)d_in[4];
    const float* Wpre0   = (const float*)d_in[5];
    const float* Wpre1   = (const float*)d_in[6];
    const float* Wpre2   = (const float*)d_in[7];
    const float* Wpost0  = (const float*)d_in[8];
    const float* Wpost1  = (const float*)d_in[9];
    const float* Wpost2  = (const float*)d_in[10];
    const float* Wsc0    = (const float*)d_in[11];
    const float* Wsc1    = (const float*)d_in[12];
    float* out = (float*)d_out;

    const int N = in_sizes[2] / 3;
    const int E = in_sizes[3];

    int* counts   = (int*)d_ws;
    int* offsets  = counts + N;
    int* cursor   = offsets + (N + 1);
    // align adj to 16B
    size_t adj_off = ((size_t)(cursor + N - (int*)d_ws) * sizeof(int) + 15) & ~(size_t)15;
    float4* adj = (float4*)((char*)d_ws + adj_off);

    hipMemsetAsync(counts, 0, (size_t)N * sizeof(int), stream);
    hist_kernel<<<(E + 255) / 256, 256, 0, stream>>>(recv, E, counts);
    scan_kernel<<<1, 1024, 0, stream>>>(counts, offsets, cursor, N);
    scatter_sh_kernel<<<(E + 255) / 256, 256, 0, stream>>>(recv, senders, pos, E, cursor, adj);
    agg_node_kernel<<<(N + 1) / 2, 256, 0, stream>>>(
        node0, node1, offsets, adj,
        Wpre0, Wpre1, Wpre2, Wpost0, Wpost1, Wpost2, Wsc0, Wsc1,
        out, N);
}